// Round 1
// baseline (2316.232 us; speedup 1.0000x reference)
//
#include <hip/hip_runtime.h>
#include <math.h>

#define TA 256
#define TB 256

// ---------------------------------------------------------------------------
// Kernel A: recurrent slot-attention core. One block per batch element,
// sequential loop over 126 timesteps. Writes slots trajectory to workspace:
// slots_traj[(b*126 + t)*128 + (s*32 + d)]
// ---------------------------------------------------------------------------
__global__ __launch_bounds__(TA, 2) void slot_recur_kernel(
    const float* __restrict__ frames, const float* __restrict__ slot_mu,
    const float* __restrict__ conv_w, const float* __restrict__ conv_b,
    const float* __restrict__ to_slot_w, const float* __restrict__ to_slot_b,
    const float* __restrict__ q_w, const float* __restrict__ k_w,
    const float* __restrict__ v_w,
    const float* __restrict__ wih, const float* __restrict__ whh,
    const float* __restrict__ bih, const float* __restrict__ bhh,
    float* __restrict__ slots_out)
{
    const int tid = threadIdx.x;
    const int b = blockIdx.x;

    // pad 36 keeps float4 alignment (36*4B = 144 = 9*16) and breaks bank ties
    __shared__ float wconv_s[32 * 36];
    __shared__ float wts_s[32 * 36];
    __shared__ float wih_s[96 * 36];
    __shared__ float whh_s[96 * 36];
    __shared__ float bconv_s[32], bts_s[32], bih_s[96], bhh_s[96];
    __shared__ float cur_s[256], prv_s[256];
    __shared__ float feat_s[16 * 36];
    __shared__ float fs_s[16 * 36];
    __shared__ float kb_s[16 * 36], vb_s[16 * 36];
    __shared__ float slots_s[4 * 36];
    __shared__ float qs_s[4 * 36];
    __shared__ float attn_s[4 * 16];
    __shared__ float upd_s[4 * 36];
    __shared__ float gi_s[4 * 96], gh_s[4 * 96];

    for (int i = tid; i < 32 * 32; i += TA) {
        int r = i >> 5, c = i & 31;
        wconv_s[r * 36 + c] = conv_w[i];
        wts_s[r * 36 + c] = to_slot_w[i];
    }
    for (int i = tid; i < 96 * 32; i += TA) {
        int r = i >> 5, c = i & 31;
        wih_s[r * 36 + c] = wih[i];
        whh_s[r * 36 + c] = whh[i];
    }
    if (tid < 32) { bconv_s[tid] = conv_b[tid]; bts_s[tid] = to_slot_b[tid]; }
    if (tid >= 128 && tid < 224) {
        int e = tid - 128;
        bih_s[e] = bih[e];
        bhh_s[e] = bhh[e];
    }
    if (tid < 128) slots_s[(tid >> 5) * 36 + (tid & 31)] = slot_mu[tid];
    __syncthreads();

    const float* fb = frames + (size_t)b * (128 * 256);
    float* so = slots_out + (size_t)b * (126 * 128);

#pragma unroll 1
    for (int t = 0; t < 126; ++t) {
        cur_s[tid] = fb[(t + 1) * 256 + tid];
        prv_s[tid] = fb[t * 256 + tid];
        __syncthreads();

        // conv 4x4/stride4 over [curr;prev] + exact GELU -> feat (16 x 32)
        for (int idx = tid; idx < 512; idx += TA) {
            int n = idx >> 5, o = idx & 31;
            int pi = (n >> 2) * 4, pj = (n & 3) * 4;
            const float* w = &wconv_s[o * 36];
            float acc = bconv_s[o];
#pragma unroll
            for (int p = 0; p < 4; ++p) {
                float4 c4 = *(const float4*)&cur_s[(pi + p) * 16 + pj];
                float4 p4 = *(const float4*)&prv_s[(pi + p) * 16 + pj];
                float4 w0 = *(const float4*)&w[p * 4];
                float4 w1 = *(const float4*)&w[16 + p * 4];
                acc += c4.x * w0.x + c4.y * w0.y + c4.z * w0.z + c4.w * w0.w;
                acc += p4.x * w1.x + p4.y * w1.y + p4.z * w1.z + p4.w * w1.w;
            }
            feat_s[n * 36 + o] = 0.5f * acc * (1.0f + erff(acc * 0.70710678118654752f));
        }
        __syncthreads();

        // to_slot: fs = feat @ to_slot_w^T + b  (16 x 32)
        for (int idx = tid; idx < 512; idx += TA) {
            int n = idx >> 5, d = idx & 31;
            const float* w = &wts_s[d * 36];
            const float* f = &feat_s[n * 36];
            float acc = bts_s[d];
#pragma unroll
            for (int c = 0; c < 32; c += 4) {
                float4 f4 = *(const float4*)&f[c];
                float4 w4 = *(const float4*)&w[c];
                acc += f4.x * w4.x + f4.y * w4.y + f4.z * w4.z + f4.w * w4.w;
            }
            fs_s[n * 36 + d] = acc;
        }
        __syncthreads();

        // k, v (weights from global; L1-hot 4KB each)
        for (int idx = tid; idx < 1024; idx += TA) {
            int n = (idx >> 5) & 15, e = idx & 31;
            const float* w = (idx < 512 ? k_w : v_w) + e * 32;
            const float* f = &fs_s[n * 36];
            float acc = 0.f;
#pragma unroll
            for (int d = 0; d < 32; d += 4) {
                float4 f4 = *(const float4*)&f[d];
                float4 w4 = *(const float4*)&w[d];
                acc += f4.x * w4.x + f4.y * w4.y + f4.z * w4.z + f4.w * w4.w;
            }
            (idx < 512 ? kb_s : vb_s)[n * 36 + e] = acc;
        }
        __syncthreads();

#pragma unroll 1
        for (int it = 0; it < 3; ++it) {
            // q = slots @ q_w^T
            if (tid < 128) {
                int s = tid >> 5, e = tid & 31;
                const float* w = q_w + e * 32;
                const float* sl = &slots_s[s * 36];
                float acc = 0.f;
#pragma unroll
                for (int d = 0; d < 32; d += 4) {
                    float4 s4 = *(const float4*)&sl[d];
                    float4 w4 = *(const float4*)&w[d];
                    acc += s4.x * w4.x + s4.y * w4.y + s4.z * w4.z + s4.w * w4.w;
                }
                qs_s[s * 36 + e] = acc;
            }
            __syncthreads();
            // logits = q . k * scale
            if (tid < 64) {
                int s = tid >> 4, n = tid & 15;
                const float* qp = &qs_s[s * 36];
                const float* kp = &kb_s[n * 36];
                float acc = 0.f;
#pragma unroll
                for (int d = 0; d < 32; d += 4) {
                    float4 q4 = *(const float4*)&qp[d];
                    float4 k4 = *(const float4*)&kp[d];
                    acc += q4.x * k4.x + q4.y * k4.y + q4.z * k4.z + q4.w * k4.w;
                }
                attn_s[s * 16 + n] = acc * 0.17677669529663687f; // 1/sqrt(32)
            }
            __syncthreads();
            // softmax over slots (axis k) per position n
            if (tid < 16) {
                int n = tid;
                float a0 = attn_s[n], a1 = attn_s[16 + n];
                float a2 = attn_s[32 + n], a3 = attn_s[48 + n];
                float m = fmaxf(fmaxf(a0, a1), fmaxf(a2, a3));
                float e0 = expf(a0 - m), e1 = expf(a1 - m);
                float e2 = expf(a2 - m), e3 = expf(a3 - m);
                float inv = 1.0f / (e0 + e1 + e2 + e3);
                attn_s[n] = e0 * inv; attn_s[16 + n] = e1 * inv;
                attn_s[32 + n] = e2 * inv; attn_s[48 + n] = e3 * inv;
            }
            __syncthreads();
            // updates = attn @ v
            if (tid < 128) {
                int s = tid >> 5, d = tid & 31;
                float acc = 0.f;
#pragma unroll
                for (int n = 0; n < 16; ++n)
                    acc += attn_s[s * 16 + n] * vb_s[n * 36 + d];
                upd_s[s * 36 + d] = acc;
            }
            __syncthreads();
            // GRU gates gi (from updates) and gh (from slots)
            for (int idx = tid; idx < 768; idx += TA) {
                int half = (idx >= 384) ? 1 : 0;
                int rr = idx - half * 384;
                int s = rr / 96, e = rr - s * 96;
                const float* w = (half ? whh_s : wih_s) + e * 36;
                const float* x = (half ? &slots_s[s * 36] : &upd_s[s * 36]);
                float acc = (half ? bhh_s : bih_s)[e];
#pragma unroll
                for (int d = 0; d < 32; d += 4) {
                    float4 x4 = *(const float4*)&x[d];
                    float4 w4 = *(const float4*)&w[d];
                    acc += x4.x * w4.x + x4.y * w4.y + x4.z * w4.z + x4.w * w4.w;
                }
                (half ? gh_s : gi_s)[s * 96 + e] = acc;
            }
            __syncthreads();
            // GRU combine (PyTorch GRUCell semantics)
            if (tid < 128) {
                int s = tid >> 5, d = tid & 31;
                const float* gi = &gi_s[s * 96];
                const float* gh = &gh_s[s * 96];
                float rg = 1.0f / (1.0f + expf(-(gi[d] + gh[d])));
                float zg = 1.0f / (1.0f + expf(-(gi[32 + d] + gh[32 + d])));
                float ng = tanhf(gi[64 + d] + rg * gh[64 + d]);
                float h = slots_s[s * 36 + d];
                slots_s[s * 36 + d] = (1.0f - zg) * ng + zg * h;
            }
            __syncthreads();
        }

        if (tid < 128) so[t * 128 + tid] = slots_s[(tid >> 5) * 36 + (tid & 31)];
        // no barrier needed: next iteration writes cur_s/prv_s (different arrays)
        // and barriers before any slots_s reader.
    }
}

// ---------------------------------------------------------------------------
// Kernel B: batched decode. GEMM (64512 x 512) = slots_traj (64512 x 128) @
// dec_w^T, fused deconv(4x4,s4) + tanh + add curr + clip. 32 rows per block.
// Thread tile: 8 cols (stride 64) x 8 rows; dec_w staged in 64-col chunks.
// ---------------------------------------------------------------------------
__global__ __launch_bounds__(TB, 1) void decode_kernel(
    const float* __restrict__ slots_traj, const float* __restrict__ frames,
    const float* __restrict__ dec_w, const float* __restrict__ dec_b,
    const float* __restrict__ deconv_w, const float* __restrict__ deconv_b,
    float* __restrict__ out)
{
    const int tid = threadIdx.x;
    const int m0 = blockIdx.x * 32;

    __shared__ float sl_s[32 * 132];   // slots tile (pad 132: 132*4=528=33*16)
    __shared__ float wch_s[64 * 132];  // dec_w chunk: 64 cols x 128 k
    __shared__ float dw_s[512];        // deconv_w (32 ch x 16)
    __shared__ float db_s[512];        // dec_b

    for (int i = tid * 4; i < 32 * 128; i += TB * 4) {
        float4 v = *(const float4*)&slots_traj[(size_t)m0 * 128 + i];
        int r = i >> 7, k = i & 127;
        *(float4*)&sl_s[r * 132 + k] = v;
    }
    for (int i = tid; i < 512; i += TB) {
        dw_s[i] = deconv_w[i];
        db_s[i] = dec_b[i];
    }
    __syncthreads();

    const int cg = tid & 63;   // col group (lane)
    const int rg = tid >> 6;   // row group (wave)

    float acc[8][8]; // [chunk=col idx][row]
#pragma unroll
    for (int ci = 0; ci < 8; ++ci)
#pragma unroll
        for (int rr = 0; rr < 8; ++rr) acc[ci][rr] = 0.f;

    const float* slb = &sl_s[(rg * 8) * 132];

#pragma unroll
    for (int ch = 0; ch < 8; ++ch) {
        // stage dec_w cols [64*ch, 64*ch+64)
        for (int i = tid * 4; i < 64 * 128; i += TB * 4) {
            float4 v = *(const float4*)&dec_w[(size_t)ch * 8192 + i];
            int cl = i >> 7, k = i & 127;
            *(float4*)&wch_s[cl * 132 + k] = v;
        }
        __syncthreads();
        const float* wrow = &wch_s[cg * 132];
#pragma unroll 4
        for (int k = 0; k < 128; k += 4) {
            float4 w4 = *(const float4*)&wrow[k];
#pragma unroll
            for (int rr = 0; rr < 8; ++rr) {
                float4 s4 = *(const float4*)&slb[rr * 132 + k];
                acc[ch][rr] += w4.x * s4.x + w4.y * s4.y + w4.z * s4.z + w4.w * s4.w;
            }
        }
        __syncthreads();
    }

    // add dec bias
#pragma unroll
    for (int ci = 0; ci < 8; ++ci) {
        float bo = db_s[cg + 64 * ci];
#pragma unroll
        for (int rr = 0; rr < 8; ++rr) acc[ci][rr] += bo;
    }

    // Deconv: thread's cols = cg + 64*ci  ->  channel = cg/16 + 4*ci,
    // spatial (i,j) = cg & 15 (constant per thread). Cross-lane reduce over
    // the 4 channel groups (lanes cg, cg^16, cg^32 within the wave).
    const int c0 = cg >> 4;
    const int sp = cg & 15;
    const int bi = sp >> 2, bj = sp & 3;
    const float db0 = deconv_b[0];

#pragma unroll 1
    for (int rr = 0; rr < 8; ++rr) {
        float part[16];
#pragma unroll
        for (int kl = 0; kl < 16; ++kl) part[kl] = 0.f;
#pragma unroll
        for (int m = 0; m < 8; ++m) {
            float sf = acc[m][rr];
            const float* dwp = &dw_s[(c0 + 4 * m) * 16];
#pragma unroll
            for (int kl = 0; kl < 16; ++kl) part[kl] += sf * dwp[kl];
        }
#pragma unroll
        for (int kl = 0; kl < 16; ++kl) {
            part[kl] += __shfl_xor(part[kl], 16);
            part[kl] += __shfl_xor(part[kl], 32);
        }
        if (c0 == 0) {
            int mrow = m0 + rg * 8 + rr;
            int bb = mrow / 126, tt = mrow - bb * 126;
            const float* fr = frames + ((size_t)bb * 128 + (tt + 1)) * 256;
            float* op = out + (size_t)mrow * 256;
#pragma unroll
            for (int kk = 0; kk < 4; ++kk) {
                int pixb = (bi * 4 + kk) * 16 + bj * 4;
                float4 c4 = *(const float4*)&fr[pixb];
                float4 o4;
                o4.x = fminf(fmaxf(c4.x + tanhf(part[kk * 4 + 0] + db0), 0.f), 1.f);
                o4.y = fminf(fmaxf(c4.y + tanhf(part[kk * 4 + 1] + db0), 0.f), 1.f);
                o4.z = fminf(fmaxf(c4.z + tanhf(part[kk * 4 + 2] + db0), 0.f), 1.f);
                o4.w = fminf(fmaxf(c4.w + tanhf(part[kk * 4 + 3] + db0), 0.f), 1.f);
                *(float4*)&op[pixb] = o4;
            }
        }
    }
}

extern "C" void kernel_launch(void* const* d_in, const int* in_sizes, int n_in,
                              void* d_out, int out_size, void* d_ws, size_t ws_size,
                              hipStream_t stream) {
    const float* frames    = (const float*)d_in[0];
    const float* slot_mu   = (const float*)d_in[1];
    const float* conv_w    = (const float*)d_in[2];
    const float* conv_b    = (const float*)d_in[3];
    const float* to_slot_w = (const float*)d_in[4];
    const float* to_slot_b = (const float*)d_in[5];
    const float* q_w       = (const float*)d_in[6];
    const float* k_w       = (const float*)d_in[7];
    const float* v_w       = (const float*)d_in[8];
    const float* gru_wih   = (const float*)d_in[9];
    const float* gru_whh   = (const float*)d_in[10];
    const float* gru_bih   = (const float*)d_in[11];
    const float* gru_bhh   = (const float*)d_in[12];
    const float* dec_w     = (const float*)d_in[13];
    const float* dec_b     = (const float*)d_in[14];
    const float* deconv_w  = (const float*)d_in[15];
    const float* deconv_b  = (const float*)d_in[16];

    float* slots_traj = (float*)d_ws; // 512*126*128 floats = 33 MB
    float* outp = (float*)d_out;

    hipLaunchKernelGGL(slot_recur_kernel, dim3(512), dim3(TA), 0, stream,
                       frames, slot_mu, conv_w, conv_b, to_slot_w, to_slot_b,
                       q_w, k_w, v_w, gru_wih, gru_whh, gru_bih, gru_bhh,
                       slots_traj);
    hipLaunchKernelGGL(decode_kernel, dim3(64512 / 32), dim3(TB), 0, stream,
                       slots_traj, frames, dec_w, dec_b, deconv_w, deconv_b,
                       outp);
}

// Round 2
// 1065.142 us; speedup vs baseline: 2.1746x; 2.1746x over previous
//
#include <hip/hip_runtime.h>
#include <math.h>

#define TA 256
#define TB 256

__device__ __forceinline__ float fast_sigmoid(float x) {
    return 1.0f / (1.0f + __expf(-x));
}
__device__ __forceinline__ float fast_tanh(float x) {
    float a = fabsf(x);
    float e = __expf(2.0f * a);
    float r = 1.0f - 2.0f / (e + 1.0f);
    return copysignf(r, x);
}
__device__ __forceinline__ float gelu_exact(float x) {
    return 0.5f * x * (1.0f + erff(x * 0.70710678118654752f));
}

// ---------------------------------------------------------------------------
// Kernel A: recurrent slot-attention core. One block per batch element,
// sequential loop over 126 timesteps. Algebraically fused:
//   Mkq = k_w^T q_w (32x32), MvW[d][e] = sum_e' v_w[e',d] wih[e,e'] (32x96)
//   A12[c][col] = sum_d wts[d,c] * (col<32 ? Mkq[d,col] : MvW[d,col-32])
//   c12[col]    = sum_d bts[d]   * (...)
// Per step: feat = gelu(conv(X)); [kq|vWT] = feat@A12 + c12;
//   3x { logits = slots@kq^T*scale (wave0, shfl-softmax) || gh = slots@whh^T;
//        gi = attn@vWT^T + bih;  GRU combine }
// Writes slots trajectory: slots_traj[(b*126+t)*128 + s*32+d]
// ---------------------------------------------------------------------------
__global__ __launch_bounds__(TA, 2) void slot_recur_kernel(
    const float* __restrict__ frames, const float* __restrict__ slot_mu,
    const float* __restrict__ conv_w, const float* __restrict__ conv_b,
    const float* __restrict__ to_slot_w, const float* __restrict__ to_slot_b,
    const float* __restrict__ q_w, const float* __restrict__ k_w,
    const float* __restrict__ v_w,
    const float* __restrict__ wih, const float* __restrict__ whh,
    const float* __restrict__ bih, const float* __restrict__ bhh,
    float* __restrict__ slots_out)
{
    const int tid = threadIdx.x;
    const int b = blockIdx.x;
    const int lane = tid & 63;
    const int wid = tid >> 6;

    // All row strides are ==4 (mod 32) and 16B-aligned: measured 0 conflicts.
    __shared__ float convW_s[32 * 36];   // conv weights [o][k=c*16+p*4+q]
    __shared__ float A12_s[32 * 132];    // fused to_slot->(kq|vW) [c][col0..127]
    __shared__ float c12_s[128];
    __shared__ float whh_s[96 * 36];     // [e][d]
    __shared__ float bih_s[96], bhh_s[96], bc_s[32];
    __shared__ float X_s[16 * 36];       // im2col patches [n][k]
    __shared__ float feat_s[16 * 36];    // [n][c]
    __shared__ float kq_s[16 * 36];      // [n][d]
    __shared__ float vWT_s[96 * 36];     // [e][n]  (also MvW temp [d*100+e] in setup)
    __shared__ float gh_s[4 * 100], gi_s[4 * 100];
    __shared__ float attn_s[4 * 20];     // [s][n]
    __shared__ float slots_s[4 * 36];    // [s][d]
    __shared__ float Mkq_s[32 * 32];     // setup temp

    // ---- Setup S0: stage raw weights (wih->A12, vw/kw/qw->whh, wts->convW)
    for (int i = tid; i < 3072; i += TA) A12_s[i] = wih[i];
    for (int i = tid; i < 1024; i += TA) {
        whh_s[i]        = v_w[i];
        whh_s[1024 + i] = k_w[i];
        whh_s[2048 + i] = q_w[i];
        convW_s[i]      = to_slot_w[i];
    }
    __syncthreads();

    // ---- Setup S1: Mkq = k_w^T q_w ; MvW[d][e] = sum_e' v_w[e',d] wih[e,e']
    for (int o = tid; o < 1024; o += TA) {
        int d = o >> 5, dp = o & 31;
        float acc = 0.f;
#pragma unroll 8
        for (int e = 0; e < 32; ++e)
            acc += whh_s[1024 + e * 32 + d] * whh_s[2048 + e * 32 + dp];
        Mkq_s[o] = acc;
    }
    for (int o = tid; o < 3072; o += TA) {
        int d = o / 96, e = o - d * 96;
        float acc = 0.f;
#pragma unroll 8
        for (int ep = 0; ep < 32; ++ep)
            acc += whh_s[ep * 32 + d] * A12_s[e * 32 + ep];
        vWT_s[d * 100 + e] = acc;  // MvW temp
    }
    __syncthreads();

    // ---- Setup S2a: A12, c12 (consumes staged wts in convW_s)
    for (int o = tid; o < 4096; o += TA) {
        int c = o >> 7, col = o & 127;
        float acc = 0.f;
        if (col < 32) {
#pragma unroll 8
            for (int d = 0; d < 32; ++d) acc += convW_s[d * 32 + c] * Mkq_s[d * 32 + col];
        } else {
            int e = col - 32;
#pragma unroll 8
            for (int d = 0; d < 32; ++d) acc += convW_s[d * 32 + c] * vWT_s[d * 100 + e];
        }
        A12_s[c * 132 + col] = acc;
    }
    if (tid < 128) {
        int col = tid;
        float acc = 0.f;
        if (col < 32) {
            for (int d = 0; d < 32; ++d) acc += to_slot_b[d] * Mkq_s[d * 32 + col];
        } else {
            int e = col - 32;
            for (int d = 0; d < 32; ++d) acc += to_slot_b[d] * vWT_s[d * 100 + e];
        }
        c12_s[col] = acc;
    }
    __syncthreads();

    // ---- Setup S2b: real convW/whh loads, biases, slots, X(t=0)
    const float* fb = frames + (size_t)b * (128 * 256);
    for (int i = tid; i < 1024; i += TA) convW_s[(i >> 5) * 36 + (i & 31)] = conv_w[i];
    for (int i = tid; i < 3072; i += TA) whh_s[(i >> 5) * 36 + (i & 31)] = whh[i];
    if (tid < 96) { bih_s[tid] = bih[tid]; bhh_s[tid] = bhh[tid]; }
    if (tid < 32) bc_s[tid] = conv_b[tid];
    if (tid < 128) slots_s[(tid >> 5) * 36 + (tid & 31)] = slot_mu[tid];
    if (tid < 128) {
        int h = tid >> 6, l = tid & 63;
        int i = l >> 2, j4 = l & 3;
        // cur = frame t+1 = 1, prv = frame t = 0
        float4 v = *(const float4*)&fb[(h ? 0 : 256) + i * 16 + j4 * 4];
        int n = (i >> 2) * 4 + j4, p = i & 3;
        *(float4*)&X_s[n * 36 + h * 16 + p * 4] = v;
    }
    __syncthreads();

    float* so = slots_out + (size_t)b * (126 * 128);

#pragma unroll 1
    for (int t = 0; t < 126; ++t) {
        // ---- P1: conv + gelu -> feat (thread = (o, n & n+8))
        {
            int o = tid & 31, ng = tid >> 5;
            const float* w = &convW_s[o * 36];
            const float* xa = &X_s[ng * 36];
            const float* xb = &X_s[(ng + 8) * 36];
            float acca = bc_s[o], accb = bc_s[o];
#pragma unroll
            for (int k = 0; k < 32; k += 4) {
                float4 w4 = *(const float4*)&w[k];
                float4 a4 = *(const float4*)&xa[k];
                float4 b4 = *(const float4*)&xb[k];
                acca += w4.x * a4.x + w4.y * a4.y + w4.z * a4.z + w4.w * a4.w;
                accb += w4.x * b4.x + w4.y * b4.y + w4.z * b4.z + w4.w * b4.w;
            }
            feat_s[ng * 36 + o] = gelu_exact(acca);
            feat_s[(ng + 8) * 36 + o] = gelu_exact(accb);
        }
        __syncthreads();

        // ---- P2: KQV = feat @ A12 + c12 -> kq_s [n][d], vWT_s [e][n]
        // plus: prefetch next step's frames (regs), write X_s at end (X dead).
        float4 pf;
        const bool havepf = (t < 125) && (tid < 128);
        if (havepf) {
            int h = tid >> 6, l = tid & 63;
            int i = l >> 2, j4 = l & 3;
            pf = *(const float4*)&fb[(t + (h ? 1 : 2)) * 256 + i * 16 + j4 * 4];
        }
        {
            const int cg = tid & 63;
            const int wv = tid >> 6;
            const int col0 = cg * 2;
            float accx[4], accy[4];
#pragma unroll
            for (int j = 0; j < 4; ++j) { accx[j] = 0.f; accy[j] = 0.f; }
            const float* f0 = &feat_s[(wv * 4 + 0) * 36];
            const float* f1 = &feat_s[(wv * 4 + 1) * 36];
            const float* f2 = &feat_s[(wv * 4 + 2) * 36];
            const float* f3 = &feat_s[(wv * 4 + 3) * 36];
#pragma unroll
            for (int c = 0; c < 32; c += 4) {
                float2 a0 = *(const float2*)&A12_s[(c + 0) * 132 + col0];
                float2 a1 = *(const float2*)&A12_s[(c + 1) * 132 + col0];
                float2 a2 = *(const float2*)&A12_s[(c + 2) * 132 + col0];
                float2 a3 = *(const float2*)&A12_s[(c + 3) * 132 + col0];
                float4 q;
                q = *(const float4*)&f0[c];
                accx[0] += a0.x * q.x + a1.x * q.y + a2.x * q.z + a3.x * q.w;
                accy[0] += a0.y * q.x + a1.y * q.y + a2.y * q.z + a3.y * q.w;
                q = *(const float4*)&f1[c];
                accx[1] += a0.x * q.x + a1.x * q.y + a2.x * q.z + a3.x * q.w;
                accy[1] += a0.y * q.x + a1.y * q.y + a2.y * q.z + a3.y * q.w;
                q = *(const float4*)&f2[c];
                accx[2] += a0.x * q.x + a1.x * q.y + a2.x * q.z + a3.x * q.w;
                accy[2] += a0.y * q.x + a1.y * q.y + a2.y * q.z + a3.y * q.w;
                q = *(const float4*)&f3[c];
                accx[3] += a0.x * q.x + a1.x * q.y + a2.x * q.z + a3.x * q.w;
                accy[3] += a0.y * q.x + a1.y * q.y + a2.y * q.z + a3.y * q.w;
            }
            float cx = c12_s[col0], cy = c12_s[col0 + 1];
#pragma unroll
            for (int j = 0; j < 4; ++j) {
                int n = wv * 4 + j;
                float vx = accx[j] + cx, vy = accy[j] + cy;
                if (col0 < 32) {
                    *(float2*)&kq_s[n * 36 + col0] = make_float2(vx, vy);
                } else {
                    vWT_s[(col0 - 32) * 36 + n] = vx;
                    vWT_s[(col0 - 31) * 36 + n] = vy;
                }
            }
        }
        if (havepf) {
            int h = tid >> 6, l = tid & 63;
            int i = l >> 2, j4 = l & 3;
            int n = (i >> 2) * 4 + j4, p = i & 3;
            *(float4*)&X_s[n * 36 + h * 16 + p * 4] = pf;
        }
        __syncthreads();

        // ---- 3 slot-attention iterations
#pragma unroll 1
        for (int it = 0; it < 3; ++it) {
            // P3a: wave0 = logits + shfl-softmax -> attn; waves1-3 = gh
            if (wid == 0) {
                int s = lane >> 4, n = lane & 15;
                const float* sp = &slots_s[s * 36];
                const float* kp = &kq_s[n * 36];
                float acc = 0.f;
#pragma unroll
                for (int d = 0; d < 32; d += 4) {
                    float4 a = *(const float4*)&sp[d];
                    float4 c = *(const float4*)&kp[d];
                    acc += a.x * c.x + a.y * c.y + a.z * c.z + a.w * c.w;
                }
                float lg = acc * 0.17677669529663687f;  // 1/sqrt(32)
                float m = fmaxf(lg, __shfl_xor(lg, 16));
                m = fmaxf(m, __shfl_xor(m, 32));
                float e = __expf(lg - m);
                float ssum = e + __shfl_xor(e, 16);
                ssum += __shfl_xor(ssum, 32);
                attn_s[s * 20 + n] = e / ssum;
            } else {
                int idx = tid - 64;          // 0..191
                int sh = idx / 96;
                int e = idx - sh * 96;
                int s0 = sh * 2;
                const float* w = &whh_s[e * 36];
                const float* sa = &slots_s[s0 * 36];
                const float* sb = &slots_s[(s0 + 1) * 36];
                float acc0 = bhh_s[e], acc1 = acc0;
#pragma unroll
                for (int d = 0; d < 32; d += 4) {
                    float4 w4 = *(const float4*)&w[d];
                    float4 a4 = *(const float4*)&sa[d];
                    float4 b4 = *(const float4*)&sb[d];
                    acc0 += w4.x * a4.x + w4.y * a4.y + w4.z * a4.z + w4.w * a4.w;
                    acc1 += w4.x * b4.x + w4.y * b4.y + w4.z * b4.z + w4.w * b4.w;
                }
                gh_s[s0 * 100 + e] = acc0;
                gh_s[(s0 + 1) * 100 + e] = acc1;
            }
            __syncthreads();

            // P3c: gi = attn @ vWT^T + bih (threads 0..191, 2 slots each)
            if (tid < 192) {
                int sh = tid / 96;
                int e = tid - sh * 96;
                int s0 = sh * 2;
                const float* vp = &vWT_s[e * 36];
                const float* a0 = &attn_s[s0 * 20];
                const float* a1 = &attn_s[(s0 + 1) * 20];
                float g0 = bih_s[e], g1 = g0;
#pragma unroll
                for (int n = 0; n < 16; n += 4) {
                    float4 v4 = *(const float4*)&vp[n];
                    float4 x0 = *(const float4*)&a0[n];
                    float4 x1 = *(const float4*)&a1[n];
                    g0 += v4.x * x0.x + v4.y * x0.y + v4.z * x0.z + v4.w * x0.w;
                    g1 += v4.x * x1.x + v4.y * x1.y + v4.z * x1.z + v4.w * x1.w;
                }
                gi_s[s0 * 100 + e] = g0;
                gi_s[(s0 + 1) * 100 + e] = g1;
            }
            __syncthreads();

            // P3d: GRU combine (PyTorch GRUCell semantics)
            if (tid < 128) {
                int s = tid >> 5, d = tid & 31;
                float gir = gi_s[s * 100 + d],      ghr = gh_s[s * 100 + d];
                float giz = gi_s[s * 100 + 32 + d], ghz = gh_s[s * 100 + 32 + d];
                float gin = gi_s[s * 100 + 64 + d], ghn = gh_s[s * 100 + 64 + d];
                float r = fast_sigmoid(gir + ghr);
                float z = fast_sigmoid(giz + ghz);
                float nn = fast_tanh(gin + r * ghn);
                float h = slots_s[s * 36 + d];
                float hn = (1.0f - z) * nn + z * h;
                slots_s[s * 36 + d] = hn;
                if (it == 2) so[t * 128 + tid] = hn;
            }
            __syncthreads();
        }
    }
}

// ---------------------------------------------------------------------------
// Kernel B: batched decode. GEMM (64512 x 512) = slots_traj (64512 x 128) @
// dec_w^T, fused deconv(4x4,s4) + tanh + add curr + clip. 32 rows per block.
// ---------------------------------------------------------------------------
__global__ __launch_bounds__(TB, 1) void decode_kernel(
    const float* __restrict__ slots_traj, const float* __restrict__ frames,
    const float* __restrict__ dec_w, const float* __restrict__ dec_b,
    const float* __restrict__ deconv_w, const float* __restrict__ deconv_b,
    float* __restrict__ out)
{
    const int tid = threadIdx.x;
    const int m0 = blockIdx.x * 32;

    __shared__ float sl_s[32 * 132];
    __shared__ float wch_s[64 * 132];
    __shared__ float dw_s[512];
    __shared__ float db_s[512];

    for (int i = tid * 4; i < 32 * 128; i += TB * 4) {
        float4 v = *(const float4*)&slots_traj[(size_t)m0 * 128 + i];
        int r = i >> 7, k = i & 127;
        *(float4*)&sl_s[r * 132 + k] = v;
    }
    for (int i = tid; i < 512; i += TB) {
        dw_s[i] = deconv_w[i];
        db_s[i] = dec_b[i];
    }
    __syncthreads();

    const int cg = tid & 63;
    const int rg = tid >> 6;

    float acc[8][8];
#pragma unroll
    for (int ci = 0; ci < 8; ++ci)
#pragma unroll
        for (int rr = 0; rr < 8; ++rr) acc[ci][rr] = 0.f;

    const float* slb = &sl_s[(rg * 8) * 132];

#pragma unroll
    for (int ch = 0; ch < 8; ++ch) {
        for (int i = tid * 4; i < 64 * 128; i += TB * 4) {
            float4 v = *(const float4*)&dec_w[(size_t)ch * 8192 + i];
            int cl = i >> 7, k = i & 127;
            *(float4*)&wch_s[cl * 132 + k] = v;
        }
        __syncthreads();
        const float* wrow = &wch_s[cg * 132];
#pragma unroll 4
        for (int k = 0; k < 128; k += 4) {
            float4 w4 = *(const float4*)&wrow[k];
#pragma unroll
            for (int rr = 0; rr < 8; ++rr) {
                float4 s4 = *(const float4*)&slb[rr * 132 + k];
                acc[ch][rr] += w4.x * s4.x + w4.y * s4.y + w4.z * s4.z + w4.w * s4.w;
            }
        }
        __syncthreads();
    }

#pragma unroll
    for (int ci = 0; ci < 8; ++ci) {
        float bo = db_s[cg + 64 * ci];
#pragma unroll
        for (int rr = 0; rr < 8; ++rr) acc[ci][rr] += bo;
    }

    const int c0 = cg >> 4;
    const int sp = cg & 15;
    const int bi = sp >> 2, bj = sp & 3;
    const float db0 = deconv_b[0];

#pragma unroll 1
    for (int rr = 0; rr < 8; ++rr) {
        float part[16];
#pragma unroll
        for (int kl = 0; kl < 16; ++kl) part[kl] = 0.f;
#pragma unroll
        for (int m = 0; m < 8; ++m) {
            float sf = acc[m][rr];
            const float* dwp = &dw_s[(c0 + 4 * m) * 16];
#pragma unroll
            for (int kl = 0; kl < 16; ++kl) part[kl] += sf * dwp[kl];
        }
#pragma unroll
        for (int kl = 0; kl < 16; ++kl) {
            part[kl] += __shfl_xor(part[kl], 16);
            part[kl] += __shfl_xor(part[kl], 32);
        }
        if (c0 == 0) {
            int mrow = m0 + rg * 8 + rr;
            int bb = mrow / 126, tt = mrow - bb * 126;
            const float* fr = frames + ((size_t)bb * 128 + (tt + 1)) * 256;
            float* op = out + (size_t)mrow * 256;
#pragma unroll
            for (int kk = 0; kk < 4; ++kk) {
                int pixb = (bi * 4 + kk) * 16 + bj * 4;
                float4 c4 = *(const float4*)&fr[pixb];
                float4 o4;
                o4.x = fminf(fmaxf(c4.x + tanhf(part[kk * 4 + 0] + db0), 0.f), 1.f);
                o4.y = fminf(fmaxf(c4.y + tanhf(part[kk * 4 + 1] + db0), 0.f), 1.f);
                o4.z = fminf(fmaxf(c4.z + tanhf(part[kk * 4 + 2] + db0), 0.f), 1.f);
                o4.w = fminf(fmaxf(c4.w + tanhf(part[kk * 4 + 3] + db0), 0.f), 1.f);
                *(float4*)&op[pixb] = o4;
            }
        }
    }
}

extern "C" void kernel_launch(void* const* d_in, const int* in_sizes, int n_in,
                              void* d_out, int out_size, void* d_ws, size_t ws_size,
                              hipStream_t stream) {
    const float* frames    = (const float*)d_in[0];
    const float* slot_mu   = (const float*)d_in[1];
    const float* conv_w    = (const float*)d_in[2];
    const float* conv_b    = (const float*)d_in[3];
    const float* to_slot_w = (const float*)d_in[4];
    const float* to_slot_b = (const float*)d_in[5];
    const float* q_w       = (const float*)d_in[6];
    const float* k_w       = (const float*)d_in[7];
    const float* v_w       = (const float*)d_in[8];
    const float* gru_wih   = (const float*)d_in[9];
    const float* gru_whh   = (const float*)d_in[10];
    const float* gru_bih   = (const float*)d_in[11];
    const float* gru_bhh   = (const float*)d_in[12];
    const float* dec_w     = (const float*)d_in[13];
    const float* dec_b     = (const float*)d_in[14];
    const float* deconv_w  = (const float*)d_in[15];
    const float* deconv_b  = (const float*)d_in[16];

    float* slots_traj = (float*)d_ws;  // 512*126*128 floats = 33 MB
    float* outp = (float*)d_out;

    hipLaunchKernelGGL(slot_recur_kernel, dim3(512), dim3(TA), 0, stream,
                       frames, slot_mu, conv_w, conv_b, to_slot_w, to_slot_b,
                       q_w, k_w, v_w, gru_wih, gru_whh, gru_bih, gru_bhh,
                       slots_traj);
    hipLaunchKernelGGL(decode_kernel, dim3(64512 / 32), dim3(TB), 0, stream,
                       slots_traj, frames, dec_w, dec_b, deconv_w, deconv_b,
                       outp);
}